// Round 2
// baseline (456.847 us; speedup 1.0000x reference)
//
#include <hip/hip_runtime.h>
#include <math.h>

#define BSZ 8
#define NSEQ 8192
#define DM 512
#define DS 16
#define CHUNK 128
#define NCHUNK (NSEQ / CHUNK)   // 64
#define NSEQS (BSZ * DS)        // 128
#define NROWS (BSZ * NSEQ)      // 65536

// ws layout (floats)
#define WS_BUT 0                          // BuT / hs_local: [NSEQS][NSEQ] (4 MB)
#define WS_C   (NSEQS * NSEQ)             // carries  [NCHUNK][NSEQS]
#define WS_HIN (WS_C + NCHUNK * NSEQS)    // prefix-in [NCHUNK][NSEQS]
#define WS_PW  (WS_HIN + NCHUNK * NSEQS)  // pow table [CHUNK][DS]

// ---------------------------------------------------------------------------
// K1: BuT[b*DS+s][n] = sum_d x[b,n,d] * Bw[s,d]
// 1-wave blocks (64 thr), 32 rows/block. lane = h*32 + r:
//   r = local row, h = k-half (cols h*256 .. h*256+255)
// x staged via LDS [2][32][36] (pad-36 -> b128 reads hit the bank floor).
// ---------------------------------------------------------------------------
__global__ __launch_bounds__(64) void k1_bu(const float* __restrict__ x,
                                            const float* __restrict__ Bw,
                                            float* __restrict__ ws) {
  __shared__ float xs[2 * 32 * 36];
  const int t = threadIdx.x;
  const int row0 = blockIdx.x * 32;
  const int r = t & 31;
  const int h = t >> 5;

  float acc[DS];
#pragma unroll
  for (int s = 0; s < DS; ++s) acc[s] = 0.f;

  for (int sl = 0; sl < 8; ++sl) {
    // ---- stage 32 rows x (2 halves x 32 cols) : 512 float4s, 8 per thread
    float4 st[8];
#pragma unroll
    for (int j = 0; j < 8; ++j) {
      const int fid = j * 64 + t;
      const int hh = fid >> 8;
      const int rr = (fid >> 3) & 31;
      const int c4 = fid & 7;
      st[j] = *reinterpret_cast<const float4*>(
          x + (size_t)(row0 + rr) * DM + hh * 256 + sl * 32 + c4 * 4);
    }
#pragma unroll
    for (int j = 0; j < 8; ++j) {
      const int fid = j * 64 + t;
      const int hh = fid >> 8;
      const int rr = (fid >> 3) & 31;
      const int c4 = fid & 7;
      *reinterpret_cast<float4*>(xs + hh * 1152 + rr * 36 + c4 * 4) = st[j];
    }
    __syncthreads();

    const int kb = h * 256 + sl * 32;
#pragma unroll
    for (int c4 = 0; c4 < 8; ++c4) {
      const float4 xv =
          *reinterpret_cast<const float4*>(xs + h * 1152 + r * 36 + c4 * 4);
#pragma unroll
      for (int s = 0; s < DS; ++s) {
        const float4 bv =
            *reinterpret_cast<const float4*>(Bw + s * DM + kb + c4 * 4);
        acc[s] += xv.x * bv.x + xv.y * bv.y + xv.z * bv.z + xv.w * bv.w;
      }
    }
    __syncthreads();
  }

  // cross-half reduce, then half 0 writes out (coalesced over n)
#pragma unroll
  for (int s = 0; s < DS; ++s) acc[s] += __shfl_xor(acc[s], 32, 64);

  if (h == 0) {
    const int row = row0 + r;
    const int b = row >> 13;            // / NSEQ
    const int n = row & (NSEQ - 1);
#pragma unroll
    for (int s = 0; s < DS; ++s)
      ws[WS_BUT + (size_t)(b * DS + s) * NSEQ + n] = acc[s];
  }
}

// ---------------------------------------------------------------------------
// K2: local chunk scans (in place) + carries.  thread = (seq, chunk)
// ---------------------------------------------------------------------------
__global__ __launch_bounds__(256) void k2_scan(const float* __restrict__ A_log,
                                               float* __restrict__ ws) {
  const int tid = blockIdx.x * 256 + threadIdx.x;  // 0..8191
  const int seq = tid >> 6;                        // 0..127
  const int ck = tid & (NCHUNK - 1);               // 0..63
  const int s = seq & (DS - 1);

  float a = expf(A_log[s]);
  a = fminf(fmaxf(a, 1e-8f), 10.0f);
  const float abar = expf(-a * (1.0f / NSEQ));

  float* p = ws + WS_BUT + (size_t)seq * NSEQ + ck * CHUNK;
  float4 v[CHUNK / 4];
#pragma unroll
  for (int i = 0; i < CHUNK / 4; ++i)
    v[i] = reinterpret_cast<const float4*>(p)[i];

  float hh = 0.f;
#pragma unroll
  for (int i = 0; i < CHUNK / 4; ++i) {
    hh = abar * hh + v[i].x; v[i].x = hh;
    hh = abar * hh + v[i].y; v[i].y = hh;
    hh = abar * hh + v[i].z; v[i].z = hh;
    hh = abar * hh + v[i].w; v[i].w = hh;
  }
#pragma unroll
  for (int i = 0; i < CHUNK / 4; ++i)
    reinterpret_cast<float4*>(p)[i] = v[i];
  ws[WS_C + ck * NSEQS + seq] = hh;
}

// ---------------------------------------------------------------------------
// K3: carry prefix over chunks (exclusive) + Abar power table. 1 block x 128.
// ---------------------------------------------------------------------------
__global__ __launch_bounds__(128) void k3_prefix(const float* __restrict__ A_log,
                                                 float* __restrict__ ws) {
  const int t = threadIdx.x;  // = seq
  const int s = t & (DS - 1);
  float a = expf(A_log[s]);
  a = fminf(fmaxf(a, 1e-8f), 10.0f);
  const float abar_c = expf(-a * ((float)CHUNK / NSEQ));

  float hh = 0.f;
#pragma unroll 8
  for (int k = 0; k < NCHUNK; ++k) {
    ws[WS_HIN + k * NSEQS + t] = hh;
    hh = abar_c * hh + ws[WS_C + k * NSEQS + t];
  }

  // pw[i][s] = Abar^(i+1);  t>>4 in 0..7 strides i, t&15 = s
#pragma unroll
  for (int i = t >> 4; i < CHUNK; i += 8)
    ws[WS_PW + i * DS + s] = expf(-a * (float)(i + 1) * (1.0f / NSEQ));
}

// ---------------------------------------------------------------------------
// K4: y[row,d] = sum_s (local[s] + pw[i][s]*Hin[s]) * Cw[d,s] + D[d]*x[row,d]
// wave per 8 rows; lane owns d = lane*8..lane*8+7 with Cw slice in VGPRs.
// ---------------------------------------------------------------------------
__global__ __launch_bounds__(256) void k4_out(const float* __restrict__ x,
                                              const float* __restrict__ Cw,
                                              const float* __restrict__ Dv,
                                              const float* __restrict__ ws,
                                              float* __restrict__ y) {
  const int lane = threadIdx.x & 63;
  const int gwave =
      __builtin_amdgcn_readfirstlane((blockIdx.x << 2) | (threadIdx.x >> 6));

  float cw[8][DS];
#pragma unroll
  for (int j = 0; j < 8; ++j)
#pragma unroll
    for (int s = 0; s < DS; ++s) cw[j][s] = Cw[(lane * 8 + j) * DS + s];
  float dv[8];
#pragma unroll
  for (int j = 0; j < 8; ++j) dv[j] = Dv[lane * 8 + j];

  for (int rr = 0; rr < 8; ++rr) {
    const int row = gwave * 8 + rr;
    const int b = row >> 13;
    const int n = row & (NSEQ - 1);
    const int ck = n >> 7;
    const int ii = n & (CHUNK - 1);

    const float* hsrow = ws + WS_BUT + (size_t)(b * DS) * NSEQ + n;
    const float* hinp = ws + WS_HIN + ck * NSEQS + b * DS;
    const float* pwp = ws + WS_PW + ii * DS;

    float hv[DS];
#pragma unroll
    for (int s = 0; s < DS; ++s)
      hv[s] = hsrow[(size_t)s * NSEQ] + pwp[s] * hinp[s];

    const float4 x0 =
        *reinterpret_cast<const float4*>(x + (size_t)row * DM + lane * 8);
    const float4 x1 =
        *reinterpret_cast<const float4*>(x + (size_t)row * DM + lane * 8 + 4);

    float o[8];
    o[0] = dv[0] * x0.x; o[1] = dv[1] * x0.y;
    o[2] = dv[2] * x0.z; o[3] = dv[3] * x0.w;
    o[4] = dv[4] * x1.x; o[5] = dv[5] * x1.y;
    o[6] = dv[6] * x1.z; o[7] = dv[7] * x1.w;
#pragma unroll
    for (int s = 0; s < DS; ++s) {
#pragma unroll
      for (int j = 0; j < 8; ++j) o[j] += hv[s] * cw[j][s];
    }
    float4 o0 = {o[0], o[1], o[2], o[3]};
    float4 o1 = {o[4], o[5], o[6], o[7]};
    *reinterpret_cast<float4*>(y + (size_t)row * DM + lane * 8) = o0;
    *reinterpret_cast<float4*>(y + (size_t)row * DM + lane * 8 + 4) = o1;
  }
}

extern "C" void kernel_launch(void* const* d_in, const int* in_sizes, int n_in,
                              void* d_out, int out_size, void* d_ws,
                              size_t ws_size, hipStream_t stream) {
  const float* x = (const float*)d_in[0];
  const float* Alog = (const float*)d_in[1];
  const float* Bw = (const float*)d_in[2];
  const float* Cw = (const float*)d_in[3];
  const float* Dv = (const float*)d_in[4];
  float* y = (float*)d_out;
  float* ws = (float*)d_ws;

  hipLaunchKernelGGL(k1_bu, dim3(NROWS / 32), dim3(64), 0, stream, x, Bw, ws);
  hipLaunchKernelGGL(k2_scan, dim3(NSEQS * NCHUNK / 256), dim3(256), 0, stream,
                     Alog, ws);
  hipLaunchKernelGGL(k3_prefix, dim3(1), dim3(128), 0, stream, Alog, ws);
  hipLaunchKernelGGL(k4_out, dim3(NROWS / (4 * 8)), dim3(256), 0, stream, x,
                     Cw, Dv, ws, y);
}

// Round 4
// 388.162 us; speedup vs baseline: 1.1769x; 1.1769x over previous
//
#include <hip/hip_runtime.h>
#include <math.h>

#define BSZ 8
#define NSEQ 8192
#define DM 512
#define DS 16
#define CHUNK 128
#define NCHUNK 64      // NSEQ/CHUNK
#define NSEQS 128      // BSZ*DS
#define NROWS 65536    // BSZ*NSEQ

// ws layout (floats). Bu / hs share the same buffer [NROWS][DS] (in-place).
#define WS_BU 0
#define WS_C   (NROWS * DS)            // carries [NCHUNK][NSEQS]
#define WS_HIN (WS_C + NCHUNK * NSEQS) // chunk-entry states [NCHUNK][NSEQS]

__device__ __forceinline__ float clamped_a(const float* A_log, int s) {
  float a = expf(A_log[s]);
  return fminf(fmaxf(a, 1e-8f), 10.0f);
}

// ---------------------------------------------------------------------------
// kA: Bu[row][s] = sum_d x[row][d] * Bw[s][d]
// Block 256 thr, 64 rows. Thread (rq,kq): rq=t>>3 owns rows row0+rq*2..+1,
// kq=t&7 owns k in [kq*64, kq*64+64). Bw read straight from global (32 KB,
// L1/L2-hot, reused by all blocks). k-reduce: shfl_xor over the 8 kq lanes.
// ---------------------------------------------------------------------------
__global__ __launch_bounds__(256) void kA_bu(const float* __restrict__ x,
                                             const float* __restrict__ Bw,
                                             float* __restrict__ ws) {
  const int t = threadIdx.x;
  const int rq = t >> 3;  // 0..31
  const int kq = t & 7;   // 0..7
  const int row0 = blockIdx.x * 64 + rq * 2;
  const float* xp0 = x + (size_t)row0 * DM + kq * 64;
  const float* xp1 = xp0 + DM;
  const float* bp0 = Bw + kq * 64;

  float acc0[DS], acc1[DS];
#pragma unroll
  for (int s = 0; s < DS; ++s) { acc0[s] = 0.f; acc1[s] = 0.f; }

#pragma unroll 2
  for (int j = 0; j < 16; ++j) {
    const float4 xv0 = *reinterpret_cast<const float4*>(xp0 + j * 4);
    const float4 xv1 = *reinterpret_cast<const float4*>(xp1 + j * 4);
#pragma unroll
    for (int s = 0; s < DS; ++s) {
      const float4 bv =
          *reinterpret_cast<const float4*>(bp0 + (size_t)s * DM + j * 4);
      acc0[s] += xv0.x * bv.x + xv0.y * bv.y + xv0.z * bv.z + xv0.w * bv.w;
      acc1[s] += xv1.x * bv.x + xv1.y * bv.y + xv1.z * bv.z + xv1.w * bv.w;
    }
  }

#pragma unroll
  for (int s = 0; s < DS; ++s) {
    acc0[s] += __shfl_xor(acc0[s], 1, 8);
    acc0[s] += __shfl_xor(acc0[s], 2, 8);
    acc0[s] += __shfl_xor(acc0[s], 4, 8);
    acc1[s] += __shfl_xor(acc1[s], 1, 8);
    acc1[s] += __shfl_xor(acc1[s], 2, 8);
    acc1[s] += __shfl_xor(acc1[s], 4, 8);
  }

  if (kq == 0) {
    float* o = ws + WS_BU + (size_t)row0 * DS;
    float4 v;
    v.x = acc0[0];  v.y = acc0[1];  v.z = acc0[2];  v.w = acc0[3];
    reinterpret_cast<float4*>(o)[0] = v;
    v.x = acc0[4];  v.y = acc0[5];  v.z = acc0[6];  v.w = acc0[7];
    reinterpret_cast<float4*>(o)[1] = v;
    v.x = acc0[8];  v.y = acc0[9];  v.z = acc0[10]; v.w = acc0[11];
    reinterpret_cast<float4*>(o)[2] = v;
    v.x = acc0[12]; v.y = acc0[13]; v.z = acc0[14]; v.w = acc0[15];
    reinterpret_cast<float4*>(o)[3] = v;
    v.x = acc1[0];  v.y = acc1[1];  v.z = acc1[2];  v.w = acc1[3];
    reinterpret_cast<float4*>(o)[4] = v;
    v.x = acc1[4];  v.y = acc1[5];  v.z = acc1[6];  v.w = acc1[7];
    reinterpret_cast<float4*>(o)[5] = v;
    v.x = acc1[8];  v.y = acc1[9];  v.z = acc1[10]; v.w = acc1[11];
    reinterpret_cast<float4*>(o)[6] = v;
    v.x = acc1[12]; v.y = acc1[13]; v.z = acc1[14]; v.w = acc1[15];
    reinterpret_cast<float4*>(o)[7] = v;
  }
}

// ---------------------------------------------------------------------------
// k2a: per (seq, chunk) local scan (seed 0) -> carry only.
// ---------------------------------------------------------------------------
__global__ __launch_bounds__(256) void k2a(const float* __restrict__ A_log,
                                           float* __restrict__ ws) {
  const int tid = blockIdx.x * 256 + threadIdx.x;  // 0..8191
  const int ck = tid >> 7;
  const int seq = tid & 127;
  const int s = seq & 15;
  const int b = seq >> 4;
  const float abar = expf(-clamped_a(A_log, s) * (1.0f / NSEQ));

  const float* p = ws + WS_BU + ((size_t)(b * NSEQ + ck * CHUNK)) * DS + s;
  float h = 0.f;
#pragma unroll 8
  for (int i = 0; i < CHUNK; ++i) h = fmaf(abar, h, p[(size_t)i * DS]);
  ws[WS_C + ck * NSEQS + seq] = h;
}

// ---------------------------------------------------------------------------
// k3: exclusive prefix over chunk carries -> Hin[ck][seq]. 1 block x 128.
// ---------------------------------------------------------------------------
__global__ __launch_bounds__(128) void k3(const float* __restrict__ A_log,
                                          float* __restrict__ ws) {
  const int t = threadIdx.x;  // seq
  const int s = t & 15;
  const float abarC = expf(-clamped_a(A_log, s) * ((float)CHUNK / NSEQ));
  float h = 0.f;
  for (int ck = 0; ck < NCHUNK; ++ck) {
    ws[WS_HIN + ck * NSEQS + t] = h;
    h = fmaf(abarC, h, ws[WS_C + ck * NSEQS + t]);
  }
}

// ---------------------------------------------------------------------------
// k2b: rescan each chunk seeded with Hin -> final hs, in place.
// ---------------------------------------------------------------------------
__global__ __launch_bounds__(256) void k2b(const float* __restrict__ A_log,
                                           float* __restrict__ ws) {
  const int tid = blockIdx.x * 256 + threadIdx.x;  // 0..8191
  const int ck = tid >> 7;
  const int seq = tid & 127;
  const int s = seq & 15;
  const int b = seq >> 4;
  const float abar = expf(-clamped_a(A_log, s) * (1.0f / NSEQ));

  float* p = ws + WS_BU + ((size_t)(b * NSEQ + ck * CHUNK)) * DS + s;
  float h = ws[WS_HIN + ck * NSEQS + seq];
#pragma unroll 8
  for (int i = 0; i < CHUNK; ++i) {
    h = fmaf(abar, h, p[(size_t)i * DS]);
    p[(size_t)i * DS] = h;
  }
}

// ---------------------------------------------------------------------------
// k4: y[row][d] = sum_s hs[row][s]*Cw[d][s] + D[d]*x[row][d]
// Block 256 = 4 waves; wave dq owns d-quarter, lane owns 2 d (cw = 32 VGPRs).
// 16 rows per block; hv = 4 contiguous broadcast float4 loads per row.
// ---------------------------------------------------------------------------
__global__ __launch_bounds__(256) void k4(const float* __restrict__ x,
                                          const float* __restrict__ Cw,
                                          const float* __restrict__ Dv,
                                          const float* __restrict__ ws,
                                          float* __restrict__ y) {
  const int lane = threadIdx.x & 63;
  const int dq = threadIdx.x >> 6;
  const int d0 = dq * 128 + lane * 2;
  const int row0 = blockIdx.x * 16;

  float cw0[DS], cw1[DS];
#pragma unroll
  for (int q = 0; q < 4; ++q) {
    const float4 a =
        *reinterpret_cast<const float4*>(Cw + (size_t)d0 * DS + q * 4);
    const float4 b =
        *reinterpret_cast<const float4*>(Cw + (size_t)(d0 + 1) * DS + q * 4);
    cw0[q * 4 + 0] = a.x; cw0[q * 4 + 1] = a.y;
    cw0[q * 4 + 2] = a.z; cw0[q * 4 + 3] = a.w;
    cw1[q * 4 + 0] = b.x; cw1[q * 4 + 1] = b.y;
    cw1[q * 4 + 2] = b.z; cw1[q * 4 + 3] = b.w;
  }
  const float2 dv = *reinterpret_cast<const float2*>(Dv + d0);
  const float* hsbase = ws + WS_BU + (size_t)row0 * DS;

#pragma unroll 2
  for (int r = 0; r < 16; ++r) {
    const int row = row0 + r;
    float hv[DS];
#pragma unroll
    for (int q = 0; q < 4; ++q) {
      const float4 h =
          *reinterpret_cast<const float4*>(hsbase + (size_t)r * DS + q * 4);
      hv[q * 4 + 0] = h.x; hv[q * 4 + 1] = h.y;
      hv[q * 4 + 2] = h.z; hv[q * 4 + 3] = h.w;
    }
    const float2 xv =
        *reinterpret_cast<const float2*>(x + (size_t)row * DM + d0);
    float o0 = dv.x * xv.x;
    float o1 = dv.y * xv.y;
#pragma unroll
    for (int s = 0; s < DS; ++s) {
      o0 = fmaf(hv[s], cw0[s], o0);
      o1 = fmaf(hv[s], cw1[s], o1);
    }
    float2 ov; ov.x = o0; ov.y = o1;
    *reinterpret_cast<float2*>(y + (size_t)row * DM + d0) = ov;
  }
}

extern "C" void kernel_launch(void* const* d_in, const int* in_sizes, int n_in,
                              void* d_out, int out_size, void* d_ws,
                              size_t ws_size, hipStream_t stream) {
  const float* x = (const float*)d_in[0];
  const float* Alog = (const float*)d_in[1];
  const float* Bw = (const float*)d_in[2];
  const float* Cw = (const float*)d_in[3];
  const float* Dv = (const float*)d_in[4];
  float* y = (float*)d_out;
  float* ws = (float*)d_ws;

  hipLaunchKernelGGL(kA_bu, dim3(NROWS / 64), dim3(256), 0, stream, x, Bw, ws);
  hipLaunchKernelGGL(k2a, dim3(NSEQS * NCHUNK / 256), dim3(256), 0, stream,
                     Alog, ws);
  hipLaunchKernelGGL(k3, dim3(1), dim3(128), 0, stream, Alog, ws);
  hipLaunchKernelGGL(k2b, dim3(NSEQS * NCHUNK / 256), dim3(256), 0, stream,
                     Alog, ws);
  hipLaunchKernelGGL(k4, dim3(NROWS / 16), dim3(256), 0, stream, x, Cw, Dv,
                     ws, y);
}

// Round 5
// 287.585 us; speedup vs baseline: 1.5886x; 1.3497x over previous
//
#include <hip/hip_runtime.h>
#include <math.h>

#define BSZ 8
#define NSEQ 8192
#define DM 512
#define DS 16
#define CHUNK 64
#define NCHUNK 128     // NSEQ/CHUNK
#define NSEQS 128      // BSZ*DS
#define NROWS 65536    // BSZ*NSEQ

// ws float offsets
#define WS_BU 0                         // [NROWS][DS]  (4 MB)
#define WS_C   (NROWS * DS)             // [NCHUNK][NSEQS]
#define WS_HIN (WS_C + NCHUNK * NSEQS)  // [NCHUNK][NSEQS]

__device__ __forceinline__ float clamped_a(const float* A_log, int s) {
  float a = expf(A_log[s]);
  return fminf(fmaxf(a, 1e-8f), 10.0f);
}

// ---------------------------------------------------------------------------
// kA: Bu[row][s] = sum_d x[row][d]*Bw[s][d], 64 rows/block, Bw in LDS.
// thread (r=t>>3, kq=t&7): rows {2r,2r+1}, k in U_j [j*32+kq*4, +4).
// Fused: tile -> LDS, 16 lanes scan 64 steps -> chunk carry.
// ---------------------------------------------------------------------------
__global__ __launch_bounds__(256) void kA(const float* __restrict__ x,
                                          const float* __restrict__ Bw,
                                          const float* __restrict__ A_log,
                                          float* __restrict__ wsBu,
                                          float* __restrict__ wsC) {
  __shared__ float bwS[DS * DM];    // 32 KB
  __shared__ float tile[64 * 20];   // pad 20 (16B-aligned rows, scan-friendly)
  const int t = threadIdx.x;
  const int row0 = blockIdx.x * 64;

#pragma unroll
  for (int j = 0; j < 8; ++j) {
    const int idx = j * 256 + t;  // 2048 float4s
    reinterpret_cast<float4*>(bwS)[idx] =
        reinterpret_cast<const float4*>(Bw)[idx];
  }
  __syncthreads();

  const int r = t >> 3;  // 0..31
  const int kq = t & 7;  // 0..7
  const float* xp0 = x + (size_t)(row0 + 2 * r) * DM;
  const float* xp1 = xp0 + DM;

  float acc0[DS], acc1[DS];
#pragma unroll
  for (int s = 0; s < DS; ++s) { acc0[s] = 0.f; acc1[s] = 0.f; }

#pragma unroll
  for (int j = 0; j < 16; ++j) {
    const int off = j * 32 + kq * 4;
    const float4 xv0 = *reinterpret_cast<const float4*>(xp0 + off);
    const float4 xv1 = *reinterpret_cast<const float4*>(xp1 + off);
#pragma unroll
    for (int s = 0; s < DS; ++s) {
      const float4 bv = *reinterpret_cast<const float4*>(bwS + s * DM + off);
      acc0[s] = fmaf(xv0.w, bv.w,
                fmaf(xv0.z, bv.z, fmaf(xv0.y, bv.y, fmaf(xv0.x, bv.x, acc0[s]))));
      acc1[s] = fmaf(xv1.w, bv.w,
                fmaf(xv1.z, bv.z, fmaf(xv1.y, bv.y, fmaf(xv1.x, bv.x, acc1[s]))));
    }
  }

#pragma unroll
  for (int s = 0; s < DS; ++s) {
    acc0[s] += __shfl_xor(acc0[s], 1, 8);
    acc0[s] += __shfl_xor(acc0[s], 2, 8);
    acc0[s] += __shfl_xor(acc0[s], 4, 8);
    acc1[s] += __shfl_xor(acc1[s], 1, 8);
    acc1[s] += __shfl_xor(acc1[s], 2, 8);
    acc1[s] += __shfl_xor(acc1[s], 4, 8);
  }

  if (kq == 0) {
    float* g0 = wsBu + (size_t)(row0 + 2 * r) * DS;
#pragma unroll
    for (int q = 0; q < 4; ++q) {
      float4 v0 = {acc0[q * 4], acc0[q * 4 + 1], acc0[q * 4 + 2], acc0[q * 4 + 3]};
      float4 v1 = {acc1[q * 4], acc1[q * 4 + 1], acc1[q * 4 + 2], acc1[q * 4 + 3]};
      reinterpret_cast<float4*>(g0)[q] = v0;
      reinterpret_cast<float4*>(g0 + DS)[q] = v1;
      *reinterpret_cast<float4*>(tile + (2 * r) * 20 + q * 4) = v0;
      *reinterpret_cast<float4*>(tile + (2 * r + 1) * 20 + q * 4) = v1;
    }
  }
  __syncthreads();

  if (t < DS) {
    const float abar = expf(-clamped_a(A_log, t) * (1.0f / NSEQ));
    float h = 0.f;
#pragma unroll
    for (int i = 0; i < CHUNK; ++i) h = fmaf(abar, h, tile[i * 20 + t]);
    const int b = blockIdx.x >> 7;    // 128 chunks per batch
    const int ck = blockIdx.x & 127;
    wsC[ck * NSEQS + b * DS + t] = h;
  }
}

// ---------------------------------------------------------------------------
// kB: exclusive prefix over chunk carries. 1 block x 128 (thread = seq).
// ---------------------------------------------------------------------------
__global__ __launch_bounds__(128) void kB(const float* __restrict__ A_log,
                                          const float* __restrict__ wsC,
                                          float* __restrict__ wsHin) {
  const int t = threadIdx.x;
  const int s = t & 15;
  const float rfac = expf(-clamped_a(A_log, s) * ((float)CHUNK / NSEQ));
  float h = 0.f;
#pragma unroll 4
  for (int ck = 0; ck < NCHUNK; ++ck) {
    wsHin[ck * NSEQS + t] = h;
    h = fmaf(rfac, h, wsC[ck * NSEQS + t]);
  }
}

// ---------------------------------------------------------------------------
// kC: per 64-row chunk: rescan Bu seeded with Hin (in LDS), then
// y[row][d] = sum_s h[row][s]*Cw[d][s] + D[d]*x[row][d].  Thread owns 2 d.
// ---------------------------------------------------------------------------
__global__ __launch_bounds__(256) void kC(const float* __restrict__ x,
                                          const float* __restrict__ Cw,
                                          const float* __restrict__ Dv,
                                          const float* __restrict__ A_log,
                                          const float* __restrict__ wsBu,
                                          const float* __restrict__ wsHin,
                                          float* __restrict__ y) {
  __shared__ float hS[64 * 20];
  __shared__ float hin[DS];
  const int t = threadIdx.x;
  const int b = blockIdx.x >> 7;
  const int ck = blockIdx.x & 127;
  const int row0 = b * NSEQ + ck * CHUNK;

  {  // Bu tile: 1024 contiguous floats, fully coalesced
    const int r = t >> 2, q = t & 3;
    const float4 v =
        *reinterpret_cast<const float4*>(wsBu + (size_t)row0 * DS + t * 4);
    *reinterpret_cast<float4*>(hS + r * 20 + q * 4) = v;
  }
  if (t < DS) hin[t] = wsHin[ck * NSEQS + b * DS + t];
  __syncthreads();

  if (t < DS) {
    const float abar = expf(-clamped_a(A_log, t) * (1.0f / NSEQ));
    float h = hin[t];
#pragma unroll
    for (int i = 0; i < CHUNK; ++i) {
      h = fmaf(abar, h, hS[i * 20 + t]);
      hS[i * 20 + t] = h;
    }
  }
  __syncthreads();

  const int d0 = t * 2;
  float cw0[DS], cw1[DS];
#pragma unroll
  for (int q = 0; q < 4; ++q) {
    const float4 a = *reinterpret_cast<const float4*>(Cw + (size_t)d0 * DS + q * 4);
    const float4 c = *reinterpret_cast<const float4*>(Cw + (size_t)(d0 + 1) * DS + q * 4);
    cw0[q * 4 + 0] = a.x; cw0[q * 4 + 1] = a.y; cw0[q * 4 + 2] = a.z; cw0[q * 4 + 3] = a.w;
    cw1[q * 4 + 0] = c.x; cw1[q * 4 + 1] = c.y; cw1[q * 4 + 2] = c.z; cw1[q * 4 + 3] = c.w;
  }
  const float dv0 = Dv[d0], dv1 = Dv[d0 + 1];

  for (int i = 0; i < CHUNK; ++i) {
    float hv[DS];
#pragma unroll
    for (int q = 0; q < 4; ++q) {
      const float4 h = *reinterpret_cast<const float4*>(hS + i * 20 + q * 4);
      hv[q * 4 + 0] = h.x; hv[q * 4 + 1] = h.y;
      hv[q * 4 + 2] = h.z; hv[q * 4 + 3] = h.w;
    }
    const float2 xv =
        *reinterpret_cast<const float2*>(x + (size_t)(row0 + i) * DM + d0);
    float o0 = dv0 * xv.x;
    float o1 = dv1 * xv.y;
#pragma unroll
    for (int s = 0; s < DS; ++s) {
      o0 = fmaf(hv[s], cw0[s], o0);
      o1 = fmaf(hv[s], cw1[s], o1);
    }
    float2 ov; ov.x = o0; ov.y = o1;
    *reinterpret_cast<float2*>(y + (size_t)(row0 + i) * DM + d0) = ov;
  }
}

extern "C" void kernel_launch(void* const* d_in, const int* in_sizes, int n_in,
                              void* d_out, int out_size, void* d_ws,
                              size_t ws_size, hipStream_t stream) {
  const float* x = (const float*)d_in[0];
  const float* Alog = (const float*)d_in[1];
  const float* Bw = (const float*)d_in[2];
  const float* Cw = (const float*)d_in[3];
  const float* Dv = (const float*)d_in[4];
  float* y = (float*)d_out;
  float* ws = (float*)d_ws;
  float* wsBu = ws + WS_BU;
  float* wsC = ws + WS_C;
  float* wsHin = ws + WS_HIN;

  hipLaunchKernelGGL(kA, dim3(NROWS / CHUNK), dim3(256), 0, stream, x, Bw,
                     Alog, wsBu, wsC);
  hipLaunchKernelGGL(kB, dim3(1), dim3(128), 0, stream, Alog, wsC, wsHin);
  hipLaunchKernelGGL(kC, dim3(NROWS / CHUNK), dim3(256), 0, stream, x, Cw, Dv,
                     Alog, wsBu, wsHin, y);
}